// Round 11
// baseline (43.025 us; speedup 1.0000x reference)
//
#include <hip/hip_runtime.h>
#include <math.h>

// Problem constants (from reference): B=8, N=512, T=8192, D=256.
#define BB 8
#define NN 512
#define TT 8192
#define DD 256

#define THREADS 256
#define BLOCKS  512        // (b, sub): 64 blocks/batch; 2 blocks/CU
#define FRAMES  128        // out-frames per block
// Max distinct segments overlapping 128 consecutive frames: durations >= 8
// -> <= ceil(128/8)+1 = 17; +1 slack.
#define MAXROWS 18

// clang ext-vector: __builtin_nontemporal_store requires a raw vector type.
typedef float v4f __attribute__((ext_vector_type(4)));

// ---------------------------------------------------------------------------
// ONE kernel writes everything (round-11):
//   - wave-level scan (registers + __shfl_up, ZERO barriers; wave 0 publishes
//     to LDS) -- replaces round-10's 16-barrier Hillis-Steele prologue
//   - out: LDS-staged x rows -> 128 KiB linear nt sweep (round-10's win)
//   - weights: full 256 KiB linear zero-read sweep per block, ones selected
//     inline (round-8's phase, inferred ~6.4 TB/s) -- no memset, no gap,
//     no partial-line RMW
//
// fp32 boundary subtlety (verified round 2): at t == start, t - c == -dur/2
// exactly; reference adds 1e-6f. For dur/2 >= 32 the half-ULP exceeds 1e-6 so
// the sum rounds back to dur/2 -> that start frame is covered by NO segment
// (weights col zero, out row zero, positions = t). Hence run-start +1 when
// uncovered.
// ---------------------------------------------------------------------------
__global__ void __launch_bounds__(THREADS)
fused_kernel(const float* __restrict__ x,
             const int* __restrict__ dur,
             float* __restrict__ positions,
             float* __restrict__ outp,
             float* __restrict__ w) {
    __shared__ int s_end[NN + 1];           // s_end[n] = start of segment n; [NN]=T
    __shared__ unsigned char s_cov[NN];
    __shared__ short seg_blk[FRAMES];       // covered seg - nlo happens later
    __shared__ int s_nlo, s_nhi;
    __shared__ float xs[(MAXROWS + 1) * DD];  // staged rows + 1 zero row

    const int bid  = blockIdx.x;
    const int b    = bid >> 6;
    const int sub  = bid & 63;
    const int tid  = threadIdx.x;
    const int lane = tid & 63;

    // ---- 1) wave-0 register scan of dur[b,:], publish to LDS ----
    if (tid < 64) {
        // lane owns durations 8*lane .. 8*lane+7 (32B/lane, coalesced)
        const int4 da = *(const int4*)(dur + b * NN + 8 * lane);
        const int4 db = *(const int4*)(dur + b * NN + 8 * lane + 4);
        int d[8] = {da.x, da.y, da.z, da.w, db.x, db.y, db.z, db.w};
        int pre[8], s = 0;
        #pragma unroll
        for (int j = 0; j < 8; ++j) { pre[j] = s; s += d[j]; }
        int incl = s;                        // inclusive wave scan of lane sums
        #pragma unroll
        for (int off = 1; off < 64; off <<= 1) {
            const int v = __shfl_up(incl, off, 64);
            if (lane >= off) incl += v;
        }
        const int base = incl - s;           // exclusive prefix for this lane
        #pragma unroll
        for (int j = 0; j < 8; ++j) {
            const int n = 8 * lane + j;
            s_end[n] = base + pre[j];
            const float h = 0.5f * (float)d[j];
            s_cov[n] = (fabsf(1e-6f - h) < h) ? 1 : 0;
        }
        if (lane == 63) s_end[NN] = incl;    // == T
    }
    __syncthreads();                         // barrier 1

    // ---- 2) segment lookup for this block's 128 frames ----
    const int f0 = sub * FRAMES;
    if (tid < FRAMES) {
        const int t = f0 + tid;
        int lo = 0, hi = NN - 1;             // find lo: s_end[lo] <= t < s_end[lo+1]
        while (lo < hi) {
            const int mid = (lo + hi) >> 1;
            if (t < s_end[mid + 1]) hi = mid; else lo = mid + 1;
        }
        const int st   = s_end[lo];
        const bool unc = (t == st) && !s_cov[lo];
        seg_blk[tid] = (short)(unc ? -1 : lo);
        positions[b * TT + t] = unc ? (float)t : (float)(t - st);
        if (tid == 0)          s_nlo = lo;
        if (tid == FRAMES - 1) s_nhi = lo;
    }
    __syncthreads();                         // barrier 2

    // ---- 3) stage x rows [nlo, nhi] (+ zero row) into LDS ----
    const int nlo   = s_nlo;
    const int nrows = s_nhi - nlo + 1;       // <= MAXROWS
    for (int idx = tid; idx < (nrows + 1) * (DD / 4); idx += THREADS) {
        const int r  = idx >> 6;             // row slot; slot nrows = zero row
        const int d4 = (idx & 63) << 2;
        v4f v = (v4f)(0.0f);
        if (r < nrows)
            v = *(const v4f*)(x + (((size_t)b * NN + nlo + r) * DD + d4));
        *(v4f*)(xs + r * DD + d4) = v;
    }
    __syncthreads();                         // barrier 3

    // ---- 4) out: 128 KiB linear sweep, LDS -> nt store (no vmem loads) ----
    float* oc = outp + ((size_t)b * TT + f0) * DD;
    #pragma unroll 4
    for (int k = 0; k < FRAMES * (DD / 4) / THREADS; ++k) {   // 32 iters
        const int idx = k * THREADS + tid;
        const int f   = idx >> 6;            // frame (uniform per wave)
        const int d4  = (idx & 63) << 2;
        const int sg  = seg_blk[f];
        const int row = (sg < 0) ? nrows : (sg - nlo);
        const v4f v = *(const v4f*)(xs + row * DD + d4);
        __builtin_nontemporal_store(v, (v4f*)(oc + ((size_t)idx << 2)));
    }

    // ---- 5) weights rows sub*8..+7: full zero-read linear sweep, ones inline ----
    const int n0 = sub * 8;
    #pragma unroll
    for (int r = 0; r < 8; ++r) {
        const int n  = n0 + r;
        const int rs = s_end[n] + (s_cov[n] ? 0 : 1);
        const int re = s_end[n + 1];
        float* wrow = w + (((size_t)b * NN + n) << 13);
        #pragma unroll
        for (int k = 0; k < 8; ++k) {
            const int t = (k * THREADS + tid) << 2;
            v4f o;
            o.x = (t     >= rs && t     < re) ? 1.0f : 0.0f;
            o.y = (t + 1 >= rs && t + 1 < re) ? 1.0f : 0.0f;
            o.z = (t + 2 >= rs && t + 2 < re) ? 1.0f : 0.0f;
            o.w = (t + 3 >= rs && t + 3 < re) ? 1.0f : 0.0f;
            __builtin_nontemporal_store(o, (v4f*)(wrow + t));
        }
    }
}

extern "C" void kernel_launch(void* const* d_in, const int* in_sizes, int n_in,
                              void* d_out, int out_size, void* d_ws, size_t ws_size,
                              hipStream_t stream) {
    const float* x  = (const float*)d_in[0];
    const int* dur  = (const int*)d_in[1];

    // Output layout: positions [B,T] | out [B,T,D] | weights [B,N,T]
    float* pos  = (float*)d_out;
    float* outp = pos + (size_t)BB * TT;
    float* w    = outp + (size_t)BB * TT * DD;

    fused_kernel<<<BLOCKS, THREADS, 0, stream>>>(x, dur, pos, outp, w);
}

// Round 12
// 37.804 us; speedup vs baseline: 1.1381x; 1.1381x over previous
//
#include <hip/hip_runtime.h>
#include <math.h>

// Problem constants (from reference): B=8, N=512, T=8192, D=256.
#define BB 8
#define NN 512
#define TT 8192
#define DD 256

#define THREADS 256
#define BLOCKS  1024       // (b, sub): 128 blocks/batch; ~4 blocks/CU
#define FRAMES  64         // out-frames per block
// Max distinct segments overlapping 64 consecutive frames: durations >= 8
// -> <= ceil(64/8)+1 = 9; +1 slack.
#define MAXROWS 10

// clang ext-vector: __builtin_nontemporal_store requires a raw vector type.
typedef float v4f __attribute__((ext_vector_type(4)));

// ---------------------------------------------------------------------------
// Round-12 = round-10 structure (memset zeros weights @6.9 TB/s; kernel does
// the rest) with the two latency fixes:
//   - barrier-free wave-0 register scan (__shfl_up, 3 block barriers total)
//     replacing the 16-barrier Hillis-Steele prologue
//   - 1024 blocks (4/CU) so resident blocks' out-sweeps hide each other's
//     scan/stage latency
// Per block: scan -> 64-frame lookup (+positions) -> stage <=10 x-rows to
// LDS (one burst; round-9 lesson: vmem->store loops run ~3.6 TB/s, LDS->store
// runs fill-class) -> 64 KiB linear nt out-sweep -> 4 ones-rows (w[rs,re)=1).
//
// fp32 boundary subtlety (verified round 2): at t == start, t - c == -dur/2
// exactly; reference adds 1e-6f. For dur/2 >= 32 the half-ULP exceeds 1e-6 so
// the sum rounds back to dur/2 -> that start frame is covered by NO segment
// (weights col zero, out row zero, positions = t). Hence run-start +1 when
// uncovered.
// ---------------------------------------------------------------------------
__global__ void __launch_bounds__(THREADS)
fused_kernel(const float* __restrict__ x,
             const int* __restrict__ dur,
             float* __restrict__ positions,
             float* __restrict__ outp,
             float* __restrict__ w) {
    __shared__ int s_end[NN + 1];           // s_end[n] = start of seg n; [NN]=T
    __shared__ unsigned char s_cov[NN];
    __shared__ short seg_blk[FRAMES];
    __shared__ int s_nlo, s_nhi;
    __shared__ float xs[(MAXROWS + 1) * DD];  // staged rows + 1 zero row

    const int bid  = blockIdx.x;
    const int b    = bid >> 7;
    const int sub  = bid & 127;
    const int tid  = threadIdx.x;
    const int lane = tid & 63;

    // ---- 1) wave-0 register scan of dur[b,:], publish to LDS ----
    if (tid < 64) {
        const int4 da = *(const int4*)(dur + b * NN + 8 * lane);
        const int4 db = *(const int4*)(dur + b * NN + 8 * lane + 4);
        int d[8] = {da.x, da.y, da.z, da.w, db.x, db.y, db.z, db.w};
        int pre[8], s = 0;
        #pragma unroll
        for (int j = 0; j < 8; ++j) { pre[j] = s; s += d[j]; }
        int incl = s;
        #pragma unroll
        for (int off = 1; off < 64; off <<= 1) {
            const int v = __shfl_up(incl, off, 64);
            if (lane >= off) incl += v;
        }
        const int base = incl - s;           // exclusive prefix for this lane
        #pragma unroll
        for (int j = 0; j < 8; ++j) {
            const int n = 8 * lane + j;
            s_end[n] = base + pre[j];
            const float h = 0.5f * (float)d[j];
            s_cov[n] = (fabsf(1e-6f - h) < h) ? 1 : 0;
        }
        if (lane == 63) s_end[NN] = incl;    // == T
    }
    __syncthreads();                         // barrier 1

    // ---- 2) segment lookup for this block's 64 frames (+ positions) ----
    const int f0 = sub * FRAMES;
    if (tid < FRAMES) {
        const int t = f0 + tid;
        int lo = 0, hi = NN - 1;             // find lo: s_end[lo] <= t < s_end[lo+1]
        while (lo < hi) {
            const int mid = (lo + hi) >> 1;
            if (t < s_end[mid + 1]) hi = mid; else lo = mid + 1;
        }
        const int st   = s_end[lo];
        const bool unc = (t == st) && !s_cov[lo];
        seg_blk[tid] = (short)(unc ? -1 : lo);
        positions[b * TT + t] = unc ? (float)t : (float)(t - st);
        if (tid == 0)          s_nlo = lo;
        if (tid == FRAMES - 1) s_nhi = lo;
    }
    __syncthreads();                         // barrier 2

    // ---- 3) stage x rows [nlo, nhi] (+ zero row) into LDS, one burst ----
    const int nlo   = s_nlo;
    const int nrows = s_nhi - nlo + 1;       // <= MAXROWS
    for (int idx = tid; idx < (nrows + 1) * (DD / 4); idx += THREADS) {
        const int r  = idx >> 6;             // row slot; slot nrows = zero row
        const int d4 = (idx & 63) << 2;
        v4f v = (v4f)(0.0f);
        if (r < nrows)
            v = *(const v4f*)(x + (((size_t)b * NN + nlo + r) * DD + d4));
        *(v4f*)(xs + r * DD + d4) = v;
    }
    __syncthreads();                         // barrier 3

    // ---- 4) out: 64 KiB linear sweep, LDS -> nt store (no vmem loads) ----
    float* oc = outp + ((size_t)b * TT + f0) * DD;
    #pragma unroll 4
    for (int k = 0; k < FRAMES * (DD / 4) / THREADS; ++k) {   // 16 iters
        const int idx = k * THREADS + tid;
        const int f   = idx >> 6;            // frame (uniform per wave)
        const int d4  = (idx & 63) << 2;
        const int sg  = seg_blk[f];
        const int row = (sg < 0) ? nrows : (sg - nlo);
        const v4f v = *(const v4f*)(xs + row * DD + d4);
        __builtin_nontemporal_store(v, (v4f*)(oc + ((size_t)idx << 2)));
    }

    // ---- 5) weight ones: rows sub*4..+3, write 1.0f on [rs, re) ----
    const int n0 = sub * 4;
    #pragma unroll
    for (int r = 0; r < 4; ++r) {
        const int n  = n0 + r;
        const int rs = s_end[n] + (s_cov[n] ? 0 : 1);
        const int re = s_end[n + 1];
        float* wrow = w + (((size_t)b * NN + n) << 13);
        for (int t = rs + tid; t < re; t += THREADS)
            wrow[t] = 1.0f;
    }
}

extern "C" void kernel_launch(void* const* d_in, const int* in_sizes, int n_in,
                              void* d_out, int out_size, void* d_ws, size_t ws_size,
                              hipStream_t stream) {
    const float* x  = (const float*)d_in[0];
    const int* dur  = (const int*)d_in[1];

    // Output layout: positions [B,T] | out [B,T,D] | weights [B,N,T]
    float* pos  = (float*)d_out;
    float* outp = pos + (size_t)BB * TT;
    float* w    = outp + (size_t)BB * TT * DD;

    // Zeros for weights via the rocclr fill path (proven 6.9 TB/s); kernel's
    // ones-writes are stream-ordered after it.
    hipMemsetAsync(w, 0, (size_t)BB * NN * TT * sizeof(float), stream);
    fused_kernel<<<BLOCKS, THREADS, 0, stream>>>(x, dur, pos, outp, w);
}

// Round 13
// 36.678 us; speedup vs baseline: 1.1730x; 1.0307x over previous
//
#include <hip/hip_runtime.h>
#include <math.h>

// Problem constants (from reference): B=8, N=512, T=8192, D=256.
#define BB 8
#define NN 512
#define TT 8192
#define DD 256

#define THREADS 256
#define BLOCKS  1024       // (b, sub): 128 blocks/batch; ~4 blocks/CU
#define FRAMES  64         // out-frames per block
// Max distinct segments overlapping 64 consecutive frames: durations >= 8
// -> <= ceil(64/8)+1 = 9; +1 slack.
#define MAXROWS 10

// clang ext-vector type for 16B vector load/store.
typedef float v4f __attribute__((ext_vector_type(4)));

// ---------------------------------------------------------------------------
// Round-13 = round-12 with ONE variable changed: the out sweep uses PLAIN
// stores instead of __builtin_nontemporal_store. Rationale: the 6.9 TB/s
// rocclr fill kernel uses plain stores (L2 write-back aggregation decouples
// store-commit from HBM); nt's L2-bypass makes each ds_read->store pair
// commit straight to HBM, serializing the sweep against DRAM latency.
//
// Structure: hipMemsetAsync zeros weights (134 MB, proven fill path); kernel
// (1024 blocks) does wave-0 register scan (__shfl_up, 3 barriers) -> 64-frame
// lookup (+positions) -> stage <=10 x-rows to LDS -> 64 KiB linear out sweep
// -> 4 ones-rows.
//
// fp32 boundary subtlety (verified round 2): at t == start, t - c == -dur/2
// exactly; reference adds 1e-6f. For dur/2 >= 32 the half-ULP exceeds 1e-6 so
// the sum rounds back to dur/2 -> that start frame is covered by NO segment
// (weights col zero, out row zero, positions = t). Hence run-start +1 when
// uncovered.
// ---------------------------------------------------------------------------
__global__ void __launch_bounds__(THREADS)
fused_kernel(const float* __restrict__ x,
             const int* __restrict__ dur,
             float* __restrict__ positions,
             float* __restrict__ outp,
             float* __restrict__ w) {
    __shared__ int s_end[NN + 1];           // s_end[n] = start of seg n; [NN]=T
    __shared__ unsigned char s_cov[NN];
    __shared__ short seg_blk[FRAMES];
    __shared__ int s_nlo, s_nhi;
    __shared__ float xs[(MAXROWS + 1) * DD];  // staged rows + 1 zero row

    const int bid  = blockIdx.x;
    const int b    = bid >> 7;
    const int sub  = bid & 127;
    const int tid  = threadIdx.x;
    const int lane = tid & 63;

    // ---- 1) wave-0 register scan of dur[b,:], publish to LDS ----
    if (tid < 64) {
        const int4 da = *(const int4*)(dur + b * NN + 8 * lane);
        const int4 db = *(const int4*)(dur + b * NN + 8 * lane + 4);
        int d[8] = {da.x, da.y, da.z, da.w, db.x, db.y, db.z, db.w};
        int pre[8], s = 0;
        #pragma unroll
        for (int j = 0; j < 8; ++j) { pre[j] = s; s += d[j]; }
        int incl = s;
        #pragma unroll
        for (int off = 1; off < 64; off <<= 1) {
            const int v = __shfl_up(incl, off, 64);
            if (lane >= off) incl += v;
        }
        const int base = incl - s;           // exclusive prefix for this lane
        #pragma unroll
        for (int j = 0; j < 8; ++j) {
            const int n = 8 * lane + j;
            s_end[n] = base + pre[j];
            const float h = 0.5f * (float)d[j];
            s_cov[n] = (fabsf(1e-6f - h) < h) ? 1 : 0;
        }
        if (lane == 63) s_end[NN] = incl;    // == T
    }
    __syncthreads();                         // barrier 1

    // ---- 2) segment lookup for this block's 64 frames (+ positions) ----
    const int f0 = sub * FRAMES;
    if (tid < FRAMES) {
        const int t = f0 + tid;
        int lo = 0, hi = NN - 1;             // find lo: s_end[lo] <= t < s_end[lo+1]
        while (lo < hi) {
            const int mid = (lo + hi) >> 1;
            if (t < s_end[mid + 1]) hi = mid; else lo = mid + 1;
        }
        const int st   = s_end[lo];
        const bool unc = (t == st) && !s_cov[lo];
        seg_blk[tid] = (short)(unc ? -1 : lo);
        positions[b * TT + t] = unc ? (float)t : (float)(t - st);
        if (tid == 0)          s_nlo = lo;
        if (tid == FRAMES - 1) s_nhi = lo;
    }
    __syncthreads();                         // barrier 2

    // ---- 3) stage x rows [nlo, nhi] (+ zero row) into LDS, one burst ----
    const int nlo   = s_nlo;
    const int nrows = s_nhi - nlo + 1;       // <= MAXROWS
    for (int idx = tid; idx < (nrows + 1) * (DD / 4); idx += THREADS) {
        const int r  = idx >> 6;             // row slot; slot nrows = zero row
        const int d4 = (idx & 63) << 2;
        v4f v = (v4f)(0.0f);
        if (r < nrows)
            v = *(const v4f*)(x + (((size_t)b * NN + nlo + r) * DD + d4));
        *(v4f*)(xs + r * DD + d4) = v;
    }
    __syncthreads();                         // barrier 3

    // ---- 4) out: 64 KiB linear sweep, LDS -> PLAIN store (A/B vs round 12) ----
    float* oc = outp + ((size_t)b * TT + f0) * DD;
    #pragma unroll 4
    for (int k = 0; k < FRAMES * (DD / 4) / THREADS; ++k) {   // 16 iters
        const int idx = k * THREADS + tid;
        const int f   = idx >> 6;            // frame (uniform per wave)
        const int d4  = (idx & 63) << 2;
        const int sg  = seg_blk[f];
        const int row = (sg < 0) ? nrows : (sg - nlo);
        const v4f v = *(const v4f*)(xs + row * DD + d4);
        *(v4f*)(oc + ((size_t)idx << 2)) = v;
    }

    // ---- 5) weight ones: rows sub*4..+3, write 1.0f on [rs, re) ----
    const int n0 = sub * 4;
    #pragma unroll
    for (int r = 0; r < 4; ++r) {
        const int n  = n0 + r;
        const int rs = s_end[n] + (s_cov[n] ? 0 : 1);
        const int re = s_end[n + 1];
        float* wrow = w + (((size_t)b * NN + n) << 13);
        for (int t = rs + tid; t < re; t += THREADS)
            wrow[t] = 1.0f;
    }
}

extern "C" void kernel_launch(void* const* d_in, const int* in_sizes, int n_in,
                              void* d_out, int out_size, void* d_ws, size_t ws_size,
                              hipStream_t stream) {
    const float* x  = (const float*)d_in[0];
    const int* dur  = (const int*)d_in[1];

    // Output layout: positions [B,T] | out [B,T,D] | weights [B,N,T]
    float* pos  = (float*)d_out;
    float* outp = pos + (size_t)BB * TT;
    float* w    = outp + (size_t)BB * TT * DD;

    // Zeros for weights via the rocclr fill path (proven 6.9 TB/s); kernel's
    // ones-writes are stream-ordered after it.
    hipMemsetAsync(w, 0, (size_t)BB * NN * TT * sizeof(float), stream);
    fused_kernel<<<BLOCKS, THREADS, 0, stream>>>(x, dur, pos, outp, w);
}

// Round 14
// 36.487 us; speedup vs baseline: 1.1792x; 1.0052x over previous
//
#include <hip/hip_runtime.h>
#include <math.h>

// Problem constants (from reference): B=8, N=512, T=8192, D=256.
#define BB 8
#define NN 512
#define TT 8192
#define DD 256

#define THREADS 256
#define BLOCKS  2048       // (b, sub): 256 blocks/batch; ~8 blocks/CU
#define FRAMES  32         // out-frames per block
// Max distinct segments overlapping 32 consecutive frames: durations >= 8
// -> floor(32/8)+1 = 5; +1 slack.
#define MAXROWS 6

// clang ext-vector type for 16B vector load/store.
typedef float v4f __attribute__((ext_vector_type(4)));

// ---------------------------------------------------------------------------
// Round-14 = round-13 with two changes:
//   (1) FRAMES 64->32, BLOCKS 1024->2048 (8 blocks/CU): doubles resident
//       out-sweeps so prologue (scan/search/stage, 3 barriers) hides under
//       other blocks' streaming.
//   (2) ones phase writes FULL 128B lines (runs padded to 32-float bounds,
//       predicated v4f stores; pad re-writes memset zeros): kills the
//       partial-line RMW fetch after the memset evicted weights from L2.
//
// Structure: hipMemsetAsync zeros weights (134 MB, rocclr fill path, ~6.9
// TB/s); kernel does wave-0 register scan (__shfl_up) -> 32-frame lookup
// (+positions) -> stage <=6 x-rows to LDS (round-9 lesson: vmem->store loops
// run ~3.6 TB/s, LDS->store runs fill-class) -> 32 KiB linear PLAIN-store
// out sweep (round-13: plain > nt) -> 2 line-aligned ones-rows.
//
// fp32 boundary subtlety (verified round 2): at t == start, t - c == -dur/2
// exactly; reference adds 1e-6f. For dur/2 >= 32 the half-ULP exceeds 1e-6 so
// the sum rounds back to dur/2 -> that start frame is covered by NO segment
// (weights col zero, out row zero, positions = t). Hence run-start +1 when
// uncovered.
// ---------------------------------------------------------------------------
__global__ void __launch_bounds__(THREADS)
fused_kernel(const float* __restrict__ x,
             const int* __restrict__ dur,
             float* __restrict__ positions,
             float* __restrict__ outp,
             float* __restrict__ w) {
    __shared__ int s_end[NN + 1];           // s_end[n] = start of seg n; [NN]=T
    __shared__ unsigned char s_cov[NN];
    __shared__ short seg_blk[FRAMES];
    __shared__ int s_nlo, s_nhi;
    __shared__ float xs[(MAXROWS + 1) * DD];  // staged rows + 1 zero row

    const int bid  = blockIdx.x;
    const int b    = bid >> 8;
    const int sub  = bid & 255;
    const int tid  = threadIdx.x;
    const int lane = tid & 63;

    // ---- 1) wave-0 register scan of dur[b,:], publish to LDS ----
    if (tid < 64) {
        const int4 da = *(const int4*)(dur + b * NN + 8 * lane);
        const int4 db = *(const int4*)(dur + b * NN + 8 * lane + 4);
        int d[8] = {da.x, da.y, da.z, da.w, db.x, db.y, db.z, db.w};
        int pre[8], s = 0;
        #pragma unroll
        for (int j = 0; j < 8; ++j) { pre[j] = s; s += d[j]; }
        int incl = s;
        #pragma unroll
        for (int off = 1; off < 64; off <<= 1) {
            const int v = __shfl_up(incl, off, 64);
            if (lane >= off) incl += v;
        }
        const int base = incl - s;           // exclusive prefix for this lane
        #pragma unroll
        for (int j = 0; j < 8; ++j) {
            const int n = 8 * lane + j;
            s_end[n] = base + pre[j];
            const float h = 0.5f * (float)d[j];
            s_cov[n] = (fabsf(1e-6f - h) < h) ? 1 : 0;
        }
        if (lane == 63) s_end[NN] = incl;    // == T
    }
    __syncthreads();                         // barrier 1

    // ---- 2) segment lookup for this block's 32 frames (+ positions) ----
    const int f0 = sub * FRAMES;
    if (tid < FRAMES) {
        const int t = f0 + tid;
        int lo = 0, hi = NN - 1;             // find lo: s_end[lo] <= t < s_end[lo+1]
        while (lo < hi) {
            const int mid = (lo + hi) >> 1;
            if (t < s_end[mid + 1]) hi = mid; else lo = mid + 1;
        }
        const int st   = s_end[lo];
        const bool unc = (t == st) && !s_cov[lo];
        seg_blk[tid] = (short)(unc ? -1 : lo);
        positions[b * TT + t] = unc ? (float)t : (float)(t - st);
        if (tid == 0)          s_nlo = lo;
        if (tid == FRAMES - 1) s_nhi = lo;
    }
    __syncthreads();                         // barrier 2

    // ---- 3) stage x rows [nlo, nhi] (+ zero row) into LDS, one burst ----
    const int nlo   = s_nlo;
    const int nrows = s_nhi - nlo + 1;       // <= MAXROWS
    for (int idx = tid; idx < (nrows + 1) * (DD / 4); idx += THREADS) {
        const int r  = idx >> 6;             // row slot; slot nrows = zero row
        const int d4 = (idx & 63) << 2;
        v4f v = (v4f)(0.0f);
        if (r < nrows)
            v = *(const v4f*)(x + (((size_t)b * NN + nlo + r) * DD + d4));
        *(v4f*)(xs + r * DD + d4) = v;
    }
    __syncthreads();                         // barrier 3

    // ---- 4) out: 32 KiB linear sweep, LDS -> plain store ----
    float* oc = outp + ((size_t)b * TT + f0) * DD;
    #pragma unroll
    for (int k = 0; k < FRAMES * (DD / 4) / THREADS; ++k) {   // 8 iters
        const int idx = k * THREADS + tid;
        const int f   = idx >> 6;            // frame (uniform per wave)
        const int d4  = (idx & 63) << 2;
        const int sg  = seg_blk[f];
        const int row = (sg < 0) ? nrows : (sg - nlo);
        const v4f v = *(const v4f*)(xs + row * DD + d4);
        *(v4f*)(oc + ((size_t)idx << 2)) = v;
    }

    // ---- 5) weight ones: rows sub*2..+1, FULL-LINE predicated writes ----
    const int n0 = sub * 2;
    #pragma unroll
    for (int r = 0; r < 2; ++r) {
        const int n  = n0 + r;
        const int rs = s_end[n] + (s_cov[n] ? 0 : 1);
        const int re = s_end[n + 1];
        const int a  = rs & ~31;             // 128B-line aligned start
        const int e  = (re + 31) & ~31;      // 128B-line aligned end
        float* wrow = w + (((size_t)b * NN + n) << 13);
        for (int t = a + (tid << 2); t < e; t += THREADS * 4) {
            v4f o;
            o.x = (t     >= rs && t     < re) ? 1.0f : 0.0f;
            o.y = (t + 1 >= rs && t + 1 < re) ? 1.0f : 0.0f;
            o.z = (t + 2 >= rs && t + 2 < re) ? 1.0f : 0.0f;
            o.w = (t + 3 >= rs && t + 3 < re) ? 1.0f : 0.0f;
            *(v4f*)(wrow + t) = o;
        }
    }
}

extern "C" void kernel_launch(void* const* d_in, const int* in_sizes, int n_in,
                              void* d_out, int out_size, void* d_ws, size_t ws_size,
                              hipStream_t stream) {
    const float* x  = (const float*)d_in[0];
    const int* dur  = (const int*)d_in[1];

    // Output layout: positions [B,T] | out [B,T,D] | weights [B,N,T]
    float* pos  = (float*)d_out;
    float* outp = pos + (size_t)BB * TT;
    float* w    = outp + (size_t)BB * TT * DD;

    // Zeros for weights via the rocclr fill path (proven 6.9 TB/s); kernel's
    // ones-writes are stream-ordered after it.
    hipMemsetAsync(w, 0, (size_t)BB * NN * TT * sizeof(float), stream);
    fused_kernel<<<BLOCKS, THREADS, 0, stream>>>(x, dur, pos, outp, w);
}

// Round 15
// 33.898 us; speedup vs baseline: 1.2692x; 1.0764x over previous
//
#include <hip/hip_runtime.h>
#include <math.h>

// Problem constants (from reference): B=8, N=512, T=8192, D=256.
#define BB 8
#define NN 512
#define TT 8192
#define DD 256

#define THREADS 256
#define BLOCKS  2048       // (b, sub): 256 blocks/batch; 8 blocks/CU
#define FRAMES  32         // out-frames per block
// Max distinct segments overlapping 32 consecutive frames: durations >= 8
// -> floor(32/8)+1 = 5; +1 slack.
#define MAXROWS 6

// clang ext-vector type for 16B vector load/store.
typedef float v4f __attribute__((ext_vector_type(4)));

// ---------------------------------------------------------------------------
// Round-15: SINGLE merged kernel, no memset (discriminates model M1 vs M2 of
// where round-14's 36.5 us goes). Differences vs round-11's failed merge:
// all PLAIN stores (round-13: nt costs ~16 ns/MB), 8 blocks/CU (vs 2), and
// the out-sweep + 2 weight-row sweeps INTERLEAVED per iteration so zero-read
// weight stores keep the store pipe fed while out's ds_reads resolve.
//
// Per block: shfl-scan prologue -> 32-frame lookup (+positions) -> stage <=6
// x-rows to LDS -> 8 macro-iters x {1 out v4f store + 2 weight v4f stores}
// = 96 KiB of linear writes.
//
// fp32 boundary subtlety (verified round 2): at t == start, t - c == -dur/2
// exactly; reference adds 1e-6f. For dur/2 >= 32 the half-ULP exceeds 1e-6 so
// the sum rounds back to dur/2 -> that start frame is covered by NO segment
// (weights col zero, out row zero, positions = t). Hence run-start +1 when
// uncovered.
// ---------------------------------------------------------------------------
__global__ void __launch_bounds__(THREADS)
merged_kernel(const float* __restrict__ x,
              const int* __restrict__ dur,
              float* __restrict__ positions,
              float* __restrict__ outp,
              float* __restrict__ w) {
    __shared__ int s_end[NN + 1];           // s_end[n] = start of seg n; [NN]=T
    __shared__ unsigned char s_cov[NN];
    __shared__ short seg_blk[FRAMES];
    __shared__ int s_nlo, s_nhi;
    __shared__ float xs[(MAXROWS + 1) * DD];  // staged rows + 1 zero row

    const int bid  = blockIdx.x;
    const int b    = bid >> 8;
    const int sub  = bid & 255;
    const int tid  = threadIdx.x;
    const int lane = tid & 63;

    // ---- 1) wave-0 register scan of dur[b,:], publish to LDS ----
    if (tid < 64) {
        const int4 da = *(const int4*)(dur + b * NN + 8 * lane);
        const int4 db = *(const int4*)(dur + b * NN + 8 * lane + 4);
        int d[8] = {da.x, da.y, da.z, da.w, db.x, db.y, db.z, db.w};
        int pre[8], s = 0;
        #pragma unroll
        for (int j = 0; j < 8; ++j) { pre[j] = s; s += d[j]; }
        int incl = s;
        #pragma unroll
        for (int off = 1; off < 64; off <<= 1) {
            const int v = __shfl_up(incl, off, 64);
            if (lane >= off) incl += v;
        }
        const int base = incl - s;           // exclusive prefix for this lane
        #pragma unroll
        for (int j = 0; j < 8; ++j) {
            const int n = 8 * lane + j;
            s_end[n] = base + pre[j];
            const float h = 0.5f * (float)d[j];
            s_cov[n] = (fabsf(1e-6f - h) < h) ? 1 : 0;
        }
        if (lane == 63) s_end[NN] = incl;    // == T
    }
    __syncthreads();                         // barrier 1

    // ---- 2) segment lookup for this block's 32 frames (+ positions) ----
    const int f0 = sub * FRAMES;
    if (tid < FRAMES) {
        const int t = f0 + tid;
        int lo = 0, hi = NN - 1;             // find lo: s_end[lo] <= t < s_end[lo+1]
        while (lo < hi) {
            const int mid = (lo + hi) >> 1;
            if (t < s_end[mid + 1]) hi = mid; else lo = mid + 1;
        }
        const int st   = s_end[lo];
        const bool unc = (t == st) && !s_cov[lo];
        seg_blk[tid] = (short)(unc ? -1 : lo);
        positions[b * TT + t] = unc ? (float)t : (float)(t - st);
        if (tid == 0)          s_nlo = lo;
        if (tid == FRAMES - 1) s_nhi = lo;
    }
    __syncthreads();                         // barrier 2

    // ---- 3) stage x rows [nlo, nhi] (+ zero row) into LDS, one burst ----
    const int nlo   = s_nlo;
    const int nrows = s_nhi - nlo + 1;       // <= MAXROWS
    for (int idx = tid; idx < (nrows + 1) * (DD / 4); idx += THREADS) {
        const int r  = idx >> 6;             // row slot; slot nrows = zero row
        const int d4 = (idx & 63) << 2;
        v4f v = (v4f)(0.0f);
        if (r < nrows)
            v = *(const v4f*)(x + (((size_t)b * NN + nlo + r) * DD + d4));
        *(v4f*)(xs + r * DD + d4) = v;
    }
    __syncthreads();                         // barrier 3

    // ---- 4) interleaved streaming: out + weight rows n0, n0+1 ----
    const int n0  = sub * 2;
    const int rs0 = s_end[n0]     + (s_cov[n0]     ? 0 : 1);
    const int re0 = s_end[n0 + 1];
    const int rs1 = s_end[n0 + 1] + (s_cov[n0 + 1] ? 0 : 1);
    const int re1 = s_end[n0 + 2];
    float* oc = outp + ((size_t)b * TT + f0) * DD;
    float* w0 = w + (((size_t)b * NN + n0) << 13);
    float* w1 = w0 + TT;

    #pragma unroll
    for (int k = 0; k < 8; ++k) {
        const int idx = k * THREADS + tid;
        // out: LDS-fed plain store (frame uniform per wave)
        const int f   = idx >> 6;
        const int d4  = (idx & 63) << 2;
        const int sg  = seg_blk[f];
        const int row = (sg < 0) ? nrows : (sg - nlo);
        const v4f v = *(const v4f*)(xs + row * DD + d4);
        *(v4f*)(oc + ((size_t)idx << 2)) = v;
        // weights: two zero-read stores (no input deps, keep store pipe fed)
        const int t = idx << 2;
        v4f o0, o1;
        o0.x = (t     >= rs0 && t     < re0) ? 1.0f : 0.0f;
        o0.y = (t + 1 >= rs0 && t + 1 < re0) ? 1.0f : 0.0f;
        o0.z = (t + 2 >= rs0 && t + 2 < re0) ? 1.0f : 0.0f;
        o0.w = (t + 3 >= rs0 && t + 3 < re0) ? 1.0f : 0.0f;
        *(v4f*)(w0 + t) = o0;
        o1.x = (t     >= rs1 && t     < re1) ? 1.0f : 0.0f;
        o1.y = (t + 1 >= rs1 && t + 1 < re1) ? 1.0f : 0.0f;
        o1.z = (t + 2 >= rs1 && t + 2 < re1) ? 1.0f : 0.0f;
        o1.w = (t + 3 >= rs1 && t + 3 < re1) ? 1.0f : 0.0f;
        *(v4f*)(w1 + t) = o1;
    }
}

extern "C" void kernel_launch(void* const* d_in, const int* in_sizes, int n_in,
                              void* d_out, int out_size, void* d_ws, size_t ws_size,
                              hipStream_t stream) {
    const float* x  = (const float*)d_in[0];
    const int* dur  = (const int*)d_in[1];

    // Output layout: positions [B,T] | out [B,T,D] | weights [B,N,T]
    float* pos  = (float*)d_out;
    float* outp = pos + (size_t)BB * TT;
    float* w    = outp + (size_t)BB * TT * DD;

    merged_kernel<<<BLOCKS, THREADS, 0, stream>>>(x, dur, pos, outp, w);
}